// Round 7
// baseline (124.323 us; speedup 1.0000x reference)
//
#include <hip/hip_runtime.h>

// ShiftLocalAttention2d 7x7, B=4, C=256 (8 heads x 32), H=W=48, fp32 I/O.
// R7: MFMA rewrite. Wave = one 16-query row. Per halo row (7):
//   S[pixel32][query16] = 2x mfma_f32_16x16x32_f16(A=K_halo, B=Q)
//   P = mask*exp(S)  (C-layout: col=lane&15=query, row=quad*4+reg=pixel)
//   P -> B-layout via per-wave LDS round trip (m120 pattern, wave_barrier)
//   O^T[ch32][query16] += 2x mfma(A=V^T, B=P)  -> query on lane&15:
//   den scaling in-lane (shfl_xor 16/32), coalesced stores.
// LDS: kl [12row][32px][36ch-shorts] 27.6KB, vl [32ch][12*32+8] 25.1KB,
// Pbuf 6x[16][36] 6.9KB = 59.6KB -> 2 blocks/CU.

#define H_IMG 48
#define W_IMG 48
#define DHEAD 32
#define NH    8
#define PLANE (H_IMG * W_IMG)      // 2304
#define TW    16
#define TH    6
#define KROWS 12                   // TH + 6 halo rows
#define KSTR  36                   // shorts per kl pixel record (72B)
#define VSTR  392                  // shorts per vl channel (784B)
#define PSTR  36                   // shorts per Pbuf query row

typedef _Float16 half_t;
typedef half_t half2_t __attribute__((ext_vector_type(2)));
typedef half_t half8_t __attribute__((ext_vector_type(8)));
typedef float  f32x4   __attribute__((ext_vector_type(4)));

__global__ __launch_bounds__(64 * TH, 2)
void natten_mfma_kernel(const float* __restrict__ q,
                        const float* __restrict__ k,
                        const float* __restrict__ v,
                        float* __restrict__ out) {
  __shared__ __align__(16) unsigned short kl[KROWS * 32 * KSTR];  // [row][px][ch]
  __shared__ __align__(16) unsigned short vl[DHEAD * VSTR];       // [ch][row*32+px]
  __shared__ __align__(16) unsigned short Pbuf[TH * TW * PSTR];   // per-wave [q][px]

  const int lane = threadIdx.x;          // 0..63
  const int wy   = threadIdx.y;          // 0..5 (wave id = query row)
  const int tid  = wy * 64 + lane;       // 0..383
  const int x0   = blockIdx.x * TW;
  const int y0   = blockIdx.y * TH;
  const size_t cbase = (size_t)blockIdx.z * DHEAD * PLANE;

  // ---- Stage K halo: task = (chpair, row, px), px fastest (coalesced) ----
  for (int i = tid; i < 16 * KROWS * 32; i += 64 * TH) {
    const int px = i & 31;
    const int t  = i >> 5;
    const int hr = t % KROWS;
    const int c  = t / KROWS;            // channel pair 0..15
    const int gy = y0 - 3 + hr, gx = x0 - 3 + px;
    union { half2_t h; unsigned u; } pk; pk.u = 0;
    if ((unsigned)gy < (unsigned)H_IMG && (unsigned)gx < (unsigned)W_IMG) {
      const float* kb = k + cbase + (size_t)(2 * c) * PLANE + gy * W_IMG + gx;
      pk.h.x = (half_t)kb[0];
      pk.h.y = (half_t)kb[PLANE];
    }
    *(unsigned*)&kl[(hr * 32 + px) * KSTR + 2 * c] = pk.u;
  }
  // ---- Stage V transposed: task = (ch, row, px-pair), pair fastest ----
  for (int i = tid; i < DHEAD * KROWS * 16; i += 64 * TH) {
    const int xp = i & 15;
    const int t  = i >> 4;
    const int hr = t % KROWS;
    const int ch = t / KROWS;            // 0..31
    const int gy = y0 - 3 + hr;
    const int gx0 = x0 - 3 + 2 * xp;
    union { half2_t h; unsigned u; } pv; pv.u = 0;
    if ((unsigned)gy < (unsigned)H_IMG) {
      const float* vb = v + cbase + (size_t)ch * PLANE + gy * W_IMG;
      if ((unsigned)gx0 < (unsigned)W_IMG)       pv.h.x = (half_t)vb[gx0];
      if ((unsigned)(gx0 + 1) < (unsigned)W_IMG) pv.h.y = (half_t)vb[gx0 + 1];
    }
    *(unsigned*)&vl[ch * VSTR + hr * 32 + 2 * xp] = pv.u;
  }

  // ---- Q B-frag: lane q=lane&15, ch = quad*8+j, prescaled, f16 ----
  const int qi = lane & 15;              // query (col) / also ch for V-frags
  const int Q  = lane >> 4;              // quad
  const int gqy = y0 + wy;
  const float S = 0.17677669529663687f;  // 1/sqrt(32)
  union { half8_t h; uint4 u; } qf;
  {
    const float* qb = q + cbase + (size_t)gqy * W_IMG + x0 + qi;
#pragma unroll
    for (int j = 0; j < 8; ++j)
      qf.h[j] = (half_t)(qb[(size_t)(Q * 8 + j) * PLANE] * S);
  }

  // ---- per-query pixel-validity mask over halo-x p=0..21 (p in [q, q+6]) ----
  const int xq = x0 + qi;
  const int lft = (xq < 3) ? xq : 3;
  const int rgt = (47 - xq < 3) ? (47 - xq) : 3;
  const unsigned pm = ((1u << (lft + rgt + 1)) - 1u) << (qi + 3 - lft);

  __syncthreads();

  unsigned short* Pb = &Pbuf[wy * TW * PSTR];
  f32x4 o0 = {0.f, 0.f, 0.f, 0.f};
  f32x4 o1 = {0.f, 0.f, 0.f, 0.f};
  float den_l = 0.f;

  // uniform 7-iteration loop (row-invalid -> pm=0, dead work, no divergence)
  for (int d = 0; d < 7; ++d) {
    const int hr = wy + d;               // halo row index, 0..11
    const int gy = gqy + d - 3;
    const unsigned pmr = ((unsigned)gy < (unsigned)H_IMG) ? pm : 0u;

    // A-frags: K pixels (lane&15) and (lane&15)+16, 8 ch at quad*8
    const unsigned short* krow = &kl[hr * 32 * KSTR];
    union { uint4 u; half8_t h; } A0, A1;
    {
      const unsigned short* p0 = &krow[qi * KSTR + Q * 8];
      const unsigned short* p1 = &krow[(qi + 16) * KSTR + Q * 8];
      uint2 a = *(const uint2*)p0, b = *(const uint2*)(p0 + 4);
      uint2 c = *(const uint2*)p1, e = *(const uint2*)(p1 + 4);
      A0.u = make_uint4(a.x, a.y, b.x, b.y);
      A1.u = make_uint4(c.x, c.y, e.x, e.y);
    }
    f32x4 zero = {0.f, 0.f, 0.f, 0.f};
    f32x4 s0 = __builtin_amdgcn_mfma_f32_16x16x32_f16(A0.h, qf.h, zero, 0, 0, 0);
    f32x4 s1 = __builtin_amdgcn_mfma_f32_16x16x32_f16(A1.h, qf.h, zero, 0, 0, 0);

    // mask + exp; this lane holds pixels 4Q+r (s0) and 16+4Q+r (s1), query qi
    union { half_t h[4]; uint2 u; } w0, w1;
#pragma unroll
    for (int r = 0; r < 4; ++r) {
      const int p0i = 4 * Q + r;
      const float e0 = (pmr >> p0i) & 1 ? __expf(s0[r]) : 0.f;
      const float e1 = (pmr >> (p0i + 16)) & 1 ? __expf(s1[r]) : 0.f;
      den_l += e0 + e1;
      w0.h[r] = (half_t)e0;
      w1.h[r] = (half_t)e1;
    }
    // P round-trip: write [q][pixel] pairs, read back B-layout (8 px / lane)
    *(uint2*)&Pb[qi * PSTR + 4 * Q]      = w0.u;
    *(uint2*)&Pb[qi * PSTR + 16 + 4 * Q] = w1.u;
    __builtin_amdgcn_wave_barrier();
    union { uint4 u; half8_t h; } Pf;
    {
      const unsigned short* pр = &Pb[qi * PSTR + 8 * Q];
      uint2 a = *(const uint2*)pр, b = *(const uint2*)(pр + 4);
      Pf.u = make_uint4(a.x, a.y, b.x, b.y);
    }
    __builtin_amdgcn_wave_barrier();

    // V^T A-frags: ch (lane&15) and +16, pixels quad*8..+7 of this halo row
    union { uint4 u; half8_t h; } V0, V1;
    V0.u = *(const uint4*)&vl[qi * VSTR + hr * 32 + 8 * Q];
    V1.u = *(const uint4*)&vl[(qi + 16) * VSTR + hr * 32 + 8 * Q];

    o0 = __builtin_amdgcn_mfma_f32_16x16x32_f16(V0.h, Pf.h, o0, 0, 0, 0);
    o1 = __builtin_amdgcn_mfma_f32_16x16x32_f16(V1.h, Pf.h, o1, 0, 0, 0);
  }

  // ---- den: sum the 4 part-lanes of each query (xor 16, 32) ----
  den_l += __shfl_xor(den_l, 16, 64);
  den_l += __shfl_xor(den_l, 32, 64);
  const float rden = 1.0f / den_l;       // center neighbor always valid

  // ---- store O^T: col=lane&15=query (coalesced x), row=quad*4+r=channel ----
  float* ob = out + cbase + (size_t)gqy * W_IMG + x0 + qi;
#pragma unroll
  for (int r = 0; r < 4; ++r) {
    ob[(size_t)(4 * Q + r) * PLANE]      = o0[r] * rden;
    ob[(size_t)(16 + 4 * Q + r) * PLANE] = o1[r] * rden;
  }
}

extern "C" void kernel_launch(void* const* d_in, const int* in_sizes, int n_in,
                              void* d_out, int out_size, void* d_ws, size_t ws_size,
                              hipStream_t stream) {
  const float* q = (const float*)d_in[0];
  const float* k = (const float*)d_in[1];
  const float* v = (const float*)d_in[2];
  float* out = (float*)d_out;

  dim3 grid(W_IMG / TW, H_IMG / TH, 4 * NH);   // (3, 8, 32) = 768 blocks
  dim3 block(64, TH);                           // 384 threads = 6 waves
  hipLaunchKernelGGL(natten_mfma_kernel, grid, block, 0, stream, q, k, v, out);
}

// Round 9
// 111.400 us; speedup vs baseline: 1.1160x; 1.1160x over previous
//
#include <hip/hip_runtime.h>

// ShiftLocalAttention2d 7x7, B=4, C=256 (8 heads x 32), H=W=48, fp32 I/O.
// R9 = R8 with compile fix (cvt_pkrtz type). Three-pole attack:
//  - NPART=2 (lane owns 16ch): halves NPART-redundant exp/dpp/mask work.
//  - CSTR=36 (18-word stride): staging b32 writes 4-way (~free); b64 reads
//    conflict-free (uniform 4 words/bank).
//  - PV in packed f16 (v_pk_fma_f16), exp2-domain softmax (scale*log2e
//    folded into Q prescale): ~24 VALU/lane-neighbor.
//  - 256thr/block tile 16x8, LDS 44.6KB -> 3 blocks/CU = 12 waves.

#define H_IMG 48
#define W_IMG 48
#define DHEAD 32
#define NH    8
#define RAD   3
#define TW    16
#define TH    8
#define HALO_W  (TW + 2*RAD)         // 22
#define HALO_H  (TH + 2*RAD)         // 14
#define HALO_PX (HALO_W * HALO_H)    // 308
#define CSTR    36                   // shorts per pixel record (72B)
#define PLANE   (H_IMG * W_IMG)      // 2304
#define NTHREADS 256

typedef _Float16 half_t;
typedef half_t half2_t __attribute__((ext_vector_type(2)));

__device__ __forceinline__ float dppadd1(float x) {   // x + lane^1 partner
  int y = __builtin_amdgcn_update_dpp(0, __float_as_int(x), 0xB1, 0xF, 0xF, true);
  return x + __int_as_float(y);
}

__global__ __launch_bounds__(NTHREADS, 3)
void natten_f32_kernel(const float* __restrict__ q,
                       const float* __restrict__ k,
                       const float* __restrict__ v,
                       float* __restrict__ out) {
  __shared__ __align__(16) unsigned short kl[(HALO_PX + 1) * CSTR];
  __shared__ __align__(16) unsigned short vl[(HALO_PX + 1) * CSTR];

  const int part = threadIdx.x;           // 0..1  (channel half; lane bit 0)
  const int qx   = threadIdx.y;           // 0..15
  const int qy   = threadIdx.z;           // 0..7
  const int tid  = part + 2 * qx + 32 * qy;
  const int x0   = blockIdx.x * TW;
  const int y0   = blockIdx.y * TH;
  const size_t cbase = (size_t)blockIdx.z * DHEAD * PLANE;

  // ---- Stage K/V halo as f16: task = (tensor, chpair, px), px fastest ----
  for (int i = tid; i < HALO_PX * 32; i += NTHREADS) {
    const int px   = i % HALO_PX;
    const int rest = i / HALO_PX;         // 0..31
    const int j    = rest & 15;           // channel pair
    const float* __restrict__ src = (rest & 16) ? v : k;
    unsigned short* dst           = (rest & 16) ? vl : kl;
    const int hy = px / HALO_W;
    const int hx = px - hy * HALO_W;
    const int gy = y0 - RAD + hy;
    const int gx = x0 - RAD + hx;
    union { half2_t h; unsigned u; } pk; pk.u = 0;
    if ((unsigned)gy < (unsigned)H_IMG && (unsigned)gx < (unsigned)W_IMG) {
      const size_t g = cbase + (size_t)(2 * j) * PLANE + (size_t)gy * W_IMG + gx;
      pk.h.x = (half_t)src[g];
      pk.h.y = (half_t)src[g + PLANE];
    }
    *(unsigned*)&dst[px * CSTR + 2 * j] = pk.u;
  }
  if (tid < CSTR) {                       // zero pad pixel (qx=15,rx=7 reads it)
    kl[HALO_PX * CSTR + tid] = 0;
    vl[HALO_PX * CSTR + tid] = 0;
  }

  // ---- This lane's 16 query channels, prescaled by (1/sqrt(d))*log2(e) ----
  const int gqx = x0 + qx, gqy = y0 + qy;
  const float Sl = 0.17677669529663687f * 1.4426950408889634f;
  const size_t qoff = cbase + (size_t)gqy * W_IMG + gqx;
  half2_t qp[8];
#pragma unroll
  for (int j = 0; j < 8; ++j) {
    qp[j].x = (half_t)(q[qoff + (size_t)(part * 16 + 2 * j) * PLANE] * Sl);
    qp[j].y = (half_t)(q[qoff + (size_t)(part * 16 + 2 * j + 1) * PLANE] * Sl);
  }

  // ---- per-lane column validity mask (row-invariant); bit7 = 0 (padding) ----
  unsigned colmask = 0;
#pragma unroll
  for (int rx = 0; rx < 7; ++rx) {
    const int gx = gqx + rx - RAD;
    if ((unsigned)gx < (unsigned)W_IMG) colmask |= (1u << rx);
  }

  __syncthreads();

  float den = 0.0f;
  half2_t o[8];
#pragma unroll
  for (int j = 0; j < 8; ++j) o[j] = (half2_t)(half_t)0;

  for (int ry = 0; ry < 2 * RAD + 1; ++ry) {
    const int gy = gqy + ry - RAD;
    const unsigned mrow = ((unsigned)gy < (unsigned)H_IMG) ? colmask : 0u;
    const int base = ((qy + ry) * HALO_W + qx) * CSTR + part * 16;
    const unsigned short* kb = &kl[base];
    const unsigned short* vb = &vl[base];
#pragma unroll
    for (int rx = 0; rx < 8; ++rx) {       // rx=7: padding slot, always masked
      union { uint2 u[4]; half2_t h[8]; } kw, vw;
      kw.u[0] = *(const uint2*)(kb + rx * CSTR);
      kw.u[1] = *(const uint2*)(kb + rx * CSTR + 4);
      kw.u[2] = *(const uint2*)(kb + rx * CSTR + 8);
      kw.u[3] = *(const uint2*)(kb + rx * CSTR + 12);
      float a0 = __builtin_amdgcn_fdot2(qp[0], kw.h[0], 0.0f, false);
      a0 = __builtin_amdgcn_fdot2(qp[1], kw.h[1], a0, false);
      a0 = __builtin_amdgcn_fdot2(qp[2], kw.h[2], a0, false);
      a0 = __builtin_amdgcn_fdot2(qp[3], kw.h[3], a0, false);
      float a1 = __builtin_amdgcn_fdot2(qp[4], kw.h[4], 0.0f, false);
      a1 = __builtin_amdgcn_fdot2(qp[5], kw.h[5], a1, false);
      a1 = __builtin_amdgcn_fdot2(qp[6], kw.h[6], a1, false);
      a1 = __builtin_amdgcn_fdot2(qp[7], kw.h[7], a1, false);
      float acc = a0 + a1;
      acc = dppadd1(acc);                  // + other channel-half (lane^1)
      acc = (mrow & (1u << rx)) ? acc : -100000.0f;
      const float p = __builtin_amdgcn_exp2f(acc);   // log2-domain softmax
      den += p;
      const half_t ph = (half_t)p;
      const half2_t p2 = {ph, ph};
      vw.u[0] = *(const uint2*)(vb + rx * CSTR);
      vw.u[1] = *(const uint2*)(vb + rx * CSTR + 4);
      vw.u[2] = *(const uint2*)(vb + rx * CSTR + 8);
      vw.u[3] = *(const uint2*)(vb + rx * CSTR + 12);
#pragma unroll
      for (int j = 0; j < 8; ++j)
        o[j] += p2 * vw.h[j];              // v_pk_fma_f16: 2 ch per inst
    }
  }

  const float rden = 1.0f / den;           // center neighbor valid -> den > 0
#pragma unroll
  for (int j = 0; j < 8; ++j) {
    out[qoff + (size_t)(part * 16 + 2 * j) * PLANE]     = (float)o[j].x * rden;
    out[qoff + (size_t)(part * 16 + 2 * j + 1) * PLANE] = (float)o[j].y * rden;
  }
}

extern "C" void kernel_launch(void* const* d_in, const int* in_sizes, int n_in,
                              void* d_out, int out_size, void* d_ws, size_t ws_size,
                              hipStream_t stream) {
  const float* q = (const float*)d_in[0];
  const float* k = (const float*)d_in[1];
  const float* v = (const float*)d_in[2];
  float* out = (float*)d_out;

  dim3 grid(W_IMG / TW, H_IMG / TH, 4 * NH);   // (3, 6, 32) = 576 blocks
  dim3 block(2, TW, TH);                        // 256 threads = 4 waves
  hipLaunchKernelGGL(natten_f32_kernel, grid, block, 0, stream, q, k, v, out);
}